// Round 14
// baseline (120.359 us; speedup 1.0000x reference)
//
#include <hip/hip_runtime.h>

namespace {
constexpr int kB = 32, kT = 30, kD = 512, kL = 196;
constexpr float kK = 2.8853900817779268f;  // 2*log2(e)
constexpr size_t kGsz = (size_t)kB * kT * kL;  // 188,160

// vwi/u + vwj/v = (vwi*v + vwj*u) * rcp(u*v): 1 rcp per 2 elements
#define PAIR(ex, ey, fx, fy, vx, vy, acc)                                   \
  {                                                                         \
    const float u_ = fmaf(ex, fx, 1.f);                                     \
    const float v_ = fmaf(ey, fy, 1.f);                                     \
    acc = fmaf(fmaf(v_, vx, u_ * vy), __builtin_amdgcn_rcpf(u_ * v_), acc); \
  }

// INSTRUMENTED: k_score and k_ctx repeat idempotent bodies `rep` times.
// Per-kernel time = dispatch_dur / rep. k_alpha already measured (3.4us, R11).

// g8[dqg][b][t][l] (l<192) = sum over 64 d of vw_d/(1+E*F).
__global__ __launch_bounds__(512) void k_score(const float* __restrict__ x,
                                               const float* __restrict__ w,
                                               const float* __restrict__ img,
                                               const float* __restrict__ vw,
                                               float* __restrict__ g8,
                                               int rep) {
  __shared__ __align__(16) float4 Fl4[16 * 64];  // [c][l ^ (c&7)]  16 KB
  __shared__ __align__(16) float4 El4[32 * 16];  // [row][c4]        8 KB
  __shared__ __align__(16) float4 vwl4[16];      //                 256 B
  int n = blockIdx.x;
  const int bg = n & 7;
  int m = n >> 3;  // 96 = 4 bi * 3 lc * 8 dqg
  const int bi = m & 3; m >>= 2;
  const int lc = m % 3;
  const int dqg = m / 3;
  const int b = bg * 4 + bi;
  const int l0 = lc * 64, d0 = dqg * 64;
  const int tid = threadIdx.x;
  for (int r = 0; r < rep; ++r) {
    asm volatile("" ::: "memory");
    // stage F = 2^(kK*img): read coalesced by-row, write XOR-swizzled
    {
      const int l = tid >> 3, c0 = tid & 7;
#pragma unroll
      for (int k = 0; k < 2; ++k) {
        const int c = c0 + 8 * k;
        const float4 v = *(const float4*)(img +
                                          ((size_t)(b * kL + l0 + l)) * kD +
                                          d0 + 4 * c);
        float4 o;
        o.x = __builtin_amdgcn_exp2f(kK * v.x);
        o.y = __builtin_amdgcn_exp2f(kK * v.y);
        o.z = __builtin_amdgcn_exp2f(kK * v.z);
        o.w = __builtin_amdgcn_exp2f(kK * v.w);
        Fl4[c * 64 + (l ^ (c & 7))] = o;
      }
    }
    // stage E = 2^(kK*(x+w)) rows 0..31 (30,31 clamp to 29; never stored)
    {
      const int row = tid >> 4, c4 = tid & 15;
      const int tc = (row < kT) ? row : kT - 1;
      const size_t gi = ((size_t)(b * kT + tc)) * kD + d0 + 4 * c4;
      const float4 xv = *(const float4*)(x + gi);
      const float4 wv4 = *(const float4*)(w + gi);
      float4 e;
      e.x = __builtin_amdgcn_exp2f(kK * (xv.x + wv4.x));
      e.y = __builtin_amdgcn_exp2f(kK * (xv.y + wv4.y));
      e.z = __builtin_amdgcn_exp2f(kK * (xv.z + wv4.z));
      e.w = __builtin_amdgcn_exp2f(kK * (xv.w + wv4.w));
      El4[row * 16 + c4] = e;
    }
    if (tid < 16) vwl4[tid] = *(const float4*)(vw + d0 + 4 * tid);
    __syncthreads();
    const int lane = tid & 63, wva = tid >> 6;  // wave owns rows r0..r0+3
    const int r0 = wva * 4;
    const float4* Ew = &El4[r0 * 16];
    float a0 = 0.f, a1 = 0.f, a2 = 0.f, a3 = 0.f;
#pragma unroll
    for (int s = 0; s < 16; ++s) {
      const float4 f = Fl4[s * 64 + (lane ^ (s & 7))];  // per-lane, swizzled
      const float4 vv = vwl4[s];                        // uniform broadcast
      const float4 E0 = Ew[s];                          // uniform broadcast
      const float4 E1 = Ew[16 + s];
      const float4 E2 = Ew[32 + s];
      const float4 E3 = Ew[48 + s];
      PAIR(E0.x, E0.y, f.x, f.y, vv.x, vv.y, a0);
      PAIR(E0.z, E0.w, f.z, f.w, vv.z, vv.w, a0);
      PAIR(E1.x, E1.y, f.x, f.y, vv.x, vv.y, a1);
      PAIR(E1.z, E1.w, f.z, f.w, vv.z, vv.w, a1);
      PAIR(E2.x, E2.y, f.x, f.y, vv.x, vv.y, a2);
      PAIR(E2.z, E2.w, f.z, f.w, vv.z, vv.w, a2);
      PAIR(E3.x, E3.y, f.x, f.y, vv.x, vv.y, a3);
      PAIR(E3.z, E3.w, f.z, f.w, vv.z, vv.w, a3);
    }
    float* gp =
        g8 + (size_t)dqg * kGsz + ((size_t)(b * kT + r0)) * kL + l0 + lane;
    gp[0] = a0;
    gp[kL] = a1;
    if (r0 + 2 < kT) gp[2 * kL] = a2;
    if (r0 + 3 < kT) gp[3 * kL] = a3;
    __syncthreads();  // protect LDS before next iteration restages
  }
}

// softmax over l: l<192 from 8 partials; l=192..195 inline (E from x+w).
__global__ __launch_bounds__(512) void k_alpha(const float* __restrict__ g8,
                                               const float* __restrict__ x,
                                               const float* __restrict__ w,
                                               const float* __restrict__ img,
                                               const float* __restrict__ vw,
                                               float* __restrict__ alpha) {
  const int qd = blockIdx.x, b = blockIdx.y;
  const int lane = threadIdx.x & 63, wv = threadIdx.x >> 6;
  const int t = qd * 8 + wv;
  if (t >= kT) return;
  const int l4 = lane & 3, dc = lane >> 2;
  const float* ir = img + ((size_t)(b * kL + 192 + l4)) * kD + dc * 32;
  const float* xr = x + ((size_t)(b * kT + t)) * kD + dc * 32;
  const float* wr = w + ((size_t)(b * kT + t)) * kD + dc * 32;
  const float* vr = vw + dc * 32;
  float tg = 0.f;
#pragma unroll
  for (int k = 0; k < 8; ++k) {
    const float4 iv = *(const float4*)(ir + 4 * k);
    const float4 xv = *(const float4*)(xr + 4 * k);
    const float4 wv4 = *(const float4*)(wr + 4 * k);
    const float4 vv = *(const float4*)(vr + 4 * k);
    const float fx = __builtin_amdgcn_exp2f(kK * iv.x);
    const float fy = __builtin_amdgcn_exp2f(kK * iv.y);
    const float fz = __builtin_amdgcn_exp2f(kK * iv.z);
    const float fw = __builtin_amdgcn_exp2f(kK * iv.w);
    const float ex = __builtin_amdgcn_exp2f(kK * (xv.x + wv4.x));
    const float ey = __builtin_amdgcn_exp2f(kK * (xv.y + wv4.y));
    const float ez = __builtin_amdgcn_exp2f(kK * (xv.z + wv4.z));
    const float ew = __builtin_amdgcn_exp2f(kK * (xv.w + wv4.w));
    PAIR(ex, ey, fx, fy, vv.x, vv.y, tg);
    PAIR(ez, ew, fz, fw, vv.z, vv.w, tg);
  }
#pragma unroll
  for (int mm = 4; mm < 64; mm <<= 1) tg += __shfl_xor(tg, mm, 64);
  const size_t base = ((size_t)(b * kT + t)) * kL;
  float q0 = 0.f, q1 = 0.f, q2 = 0.f;
#pragma unroll
  for (int p = 0; p < 8; ++p) {
    const float* gp = g8 + (size_t)p * kGsz + base;
    q0 += gp[lane];
    q1 += gp[lane + 64];
    q2 += gp[lane + 128];
  }
  q0 *= kK; q1 *= kK; q2 *= kK;
  float q3 = (lane < 4) ? tg * kK : __builtin_inff();
  float m = fminf(fminf(q0, q1), fminf(q2, q3));
#pragma unroll
  for (int mm = 1; mm < 64; mm <<= 1) m = fminf(m, __shfl_xor(m, mm, 64));
  const float e0 = __builtin_amdgcn_exp2f(m - q0);
  const float e1 = __builtin_amdgcn_exp2f(m - q1);
  const float e2 = __builtin_amdgcn_exp2f(m - q2);
  const float e3 = (lane < 4) ? __builtin_amdgcn_exp2f(m - q3) : 0.f;
  float s = e0 + e1 + e2 + e3;
#pragma unroll
  for (int mm = 1; mm < 64; mm <<= 1) s += __shfl_xor(s, mm, 64);
  const float rs = __builtin_amdgcn_rcpf(s);
  float* ab = alpha + base;
  ab[lane] = e0 * rs;
  ab[lane + 64] = e1 * rs;
  ab[lane + 128] = e2 * rs;
  if (lane < 4) ab[lane + 192] = e3 * rs;
}

// context[b][t][d] = sum_l img[b][l][d]*alpha[b][t][l].
__global__ __launch_bounds__(256) void k_ctx(const float* __restrict__ img,
                                             const float* __restrict__ alpha,
                                             float* __restrict__ out,
                                             int rep) {
  __shared__ __align__(16) float red[4][5][256];  // 20 KB
  int n = blockIdx.x;
  const int bg = n & 7;
  int m = n >> 3;  // 48 = 4 bi * 6 tg * 2 dh
  const int bi = m & 3; m >>= 2;
  const int tg = m % 6;
  const int dh = m / 6;
  const int b = bg * 4 + bi;
  const int t0 = tg * 5, d0 = dh * 256;
  const int tid = threadIdx.x;
  const int lane = tid & 63;
  const int lru = __builtin_amdgcn_readfirstlane(tid >> 6);
  for (int r = 0; r < rep; ++r) {
    asm volatile("" ::: "memory");
    const float* ap = alpha + ((size_t)(b * kT + t0)) * kL + lru * 49;
    const float* ip = img + ((size_t)(b * kL + lru * 49)) * kD + d0 + 4 * lane;
    float4 acc[5];
#pragma unroll
    for (int j = 0; j < 5; ++j) acc[j] = {0.f, 0.f, 0.f, 0.f};
    auto loadI = [&](float4* dst, int bb) {
#pragma unroll
      for (int j = 0; j < 8; ++j)
        dst[j] = *(const float4*)(ip + (size_t)(bb * 8 + j) * kD);
    };
    auto compI = [&](const float4* f, int bb) {
#pragma unroll
      for (int j = 0; j < 8; ++j) {
        const int i = bb * 8 + j;
        const float a0 = ap[i];
        const float a1 = ap[kL + i];
        const float a2 = ap[2 * kL + i];
        const float a3 = ap[3 * kL + i];
        const float a4 = ap[4 * kL + i];
        acc[0].x = fmaf(f[j].x, a0, acc[0].x); acc[0].y = fmaf(f[j].y, a0, acc[0].y);
        acc[0].z = fmaf(f[j].z, a0, acc[0].z); acc[0].w = fmaf(f[j].w, a0, acc[0].w);
        acc[1].x = fmaf(f[j].x, a1, acc[1].x); acc[1].y = fmaf(f[j].y, a1, acc[1].y);
        acc[1].z = fmaf(f[j].z, a1, acc[1].z); acc[1].w = fmaf(f[j].w, a1, acc[1].w);
        acc[2].x = fmaf(f[j].x, a2, acc[2].x); acc[2].y = fmaf(f[j].y, a2, acc[2].y);
        acc[2].z = fmaf(f[j].z, a2, acc[2].z); acc[2].w = fmaf(f[j].w, a2, acc[2].w);
        acc[3].x = fmaf(f[j].x, a3, acc[3].x); acc[3].y = fmaf(f[j].y, a3, acc[3].y);
        acc[3].z = fmaf(f[j].z, a3, acc[3].z); acc[3].w = fmaf(f[j].w, a3, acc[3].w);
        acc[4].x = fmaf(f[j].x, a4, acc[4].x); acc[4].y = fmaf(f[j].y, a4, acc[4].y);
        acc[4].z = fmaf(f[j].z, a4, acc[4].z); acc[4].w = fmaf(f[j].w, a4, acc[4].w);
      }
    };
    float4 fA[8], fB[8];
    loadI(fA, 0);
    loadI(fB, 1); compI(fA, 0);
    loadI(fA, 2); compI(fB, 1);
    loadI(fB, 3); compI(fA, 2);
    loadI(fA, 4); compI(fB, 3);
    loadI(fB, 5); compI(fA, 4);
    compI(fB, 5);
    {  // tail l-index 48 of this quarter
      const float4 v = *(const float4*)(ip + (size_t)48 * kD);
      const int i = 48;
      const float a0 = ap[i], a1 = ap[kL + i], a2 = ap[2 * kL + i],
                  a3 = ap[3 * kL + i], a4 = ap[4 * kL + i];
      acc[0].x = fmaf(v.x, a0, acc[0].x); acc[0].y = fmaf(v.y, a0, acc[0].y);
      acc[0].z = fmaf(v.z, a0, acc[0].z); acc[0].w = fmaf(v.w, a0, acc[0].w);
      acc[1].x = fmaf(v.x, a1, acc[1].x); acc[1].y = fmaf(v.y, a1, acc[1].y);
      acc[1].z = fmaf(v.z, a1, acc[1].z); acc[1].w = fmaf(v.w, a1, acc[1].w);
      acc[2].x = fmaf(v.x, a2, acc[2].x); acc[2].y = fmaf(v.y, a2, acc[2].y);
      acc[2].z = fmaf(v.z, a2, acc[2].z); acc[2].w = fmaf(v.w, a2, acc[2].w);
      acc[3].x = fmaf(v.x, a3, acc[3].x); acc[3].y = fmaf(v.y, a3, acc[3].y);
      acc[3].z = fmaf(v.z, a3, acc[3].z); acc[3].w = fmaf(v.w, a3, acc[3].w);
      acc[4].x = fmaf(v.x, a4, acc[4].x); acc[4].y = fmaf(v.y, a4, acc[4].y);
      acc[4].z = fmaf(v.z, a4, acc[4].z); acc[4].w = fmaf(v.w, a4, acc[4].w);
    }
#pragma unroll
    for (int j = 0; j < 5; ++j) *(float4*)&red[lru][j][4 * lane] = acc[j];
    __syncthreads();
#pragma unroll
    for (int j = 0; j < 5; ++j) {
      const float s =
          red[0][j][tid] + red[1][j][tid] + red[2][j][tid] + red[3][j][tid];
      out[((size_t)(b * kT + t0 + j)) * kD + d0 + tid] = s;
    }
    __syncthreads();  // protect red[] before next iteration
  }
}
}  // namespace

extern "C" void kernel_launch(void* const* d_in, const int* in_sizes, int n_in,
                              void* d_out, int out_size, void* d_ws, size_t ws_size,
                              hipStream_t stream) {
  const float* x = (const float*)d_in[0];
  const float* wordemb = (const float*)d_in[1];
  const float* img = (const float*)d_in[2];
  const float* vw = (const float*)d_in[3];
  // v_b (d_in[4]) cancels in the softmax along with sum(v_w) — unused by design.
  float* out = (float*)d_out;
  float* g8 = (float*)d_ws;        // 6.02 MB
  float* alpha = g8 + 8 * kGsz;    // 0.75 MB
  // Instrumented: rep pushes k_score/k_ctx above the ~40us fill floor.
  hipLaunchKernelGGL(k_score, dim3(768), dim3(512), 0, stream, x, wordemb, img,
                     vw, g8, 5);
  hipLaunchKernelGGL(k_alpha, dim3(4, kB), dim3(512), 0, stream, g8, x, wordemb,
                     img, vw, alpha);
  hipLaunchKernelGGL(k_ctx, dim3(384), dim3(256), 0, stream, img, alpha, out,
                     12);
}

// Round 15
// 31.136 us; speedup vs baseline: 3.8656x; 3.8656x over previous
//
#include <hip/hip_runtime.h>

namespace {
constexpr int kB = 32, kT = 30, kD = 512, kL = 196;
constexpr float kK = 2.8853900817779268f;  // 2*log2(e)
constexpr size_t kGsz = (size_t)kB * kT * kL;  // 188,160

// vwi/u + vwj/v = (vwi*v + vwj*u) * rcp(u*v): 1 rcp per 2 elements
#define PAIR(ex, ey, fx, fy, vx, vy, acc)                                   \
  {                                                                         \
    const float u_ = fmaf(ex, fx, 1.f);                                     \
    const float v_ = fmaf(ey, fy, 1.f);                                     \
    acc = fmaf(fmaf(v_, vx, u_ * vy), __builtin_amdgcn_rcpf(u_ * v_), acc); \
  }

// g8[dqg][b][t][l] (l<192) = sum over 64 d of vw_d/(1+E*F).
// 768 blocks (bg:8 XCD-affine x bi:4 x lc:3 x dqg:8) x 512 thr (8 waves).
// Waves = (tg:4 t-groups x dh:2 d-halves); wave = 8t x 32d x 64l ->
// per s-step 10 LDS reads per 2048 elements (was 6 per 1024).
// dh halves merge partials via LDS scratch; g8 layout unchanged.
__global__ __launch_bounds__(512) void k_score(const float* __restrict__ x,
                                               const float* __restrict__ w,
                                               const float* __restrict__ img,
                                               const float* __restrict__ vw,
                                               float* __restrict__ g8) {
  __shared__ __align__(16) float4 Fl4[16 * 64];  // [c][l ^ (c&7)]  16 KB
  __shared__ __align__(16) float4 El4[32 * 16];  // [row][c4]        8 KB
  __shared__ __align__(16) float4 vwl4[16];      //                 256 B
  __shared__ __align__(16) float sc[4 * 8 * 64];  // dh-merge scratch 8 KB
  int n = blockIdx.x;
  const int bg = n & 7;
  int m = n >> 3;  // 96 = 4 bi * 3 lc * 8 dqg
  const int bi = m & 3; m >>= 2;
  const int lc = m % 3;
  const int dqg = m / 3;
  const int b = bg * 4 + bi;
  const int l0 = lc * 64, d0 = dqg * 64;
  const int tid = threadIdx.x;
  // stage F = 2^(kK*img): 1024 float4s; 16 lanes/row -> 256B contiguous reads
#pragma unroll
  for (int k = 0; k < 2; ++k) {
    const int i = tid + k * 512;
    const int l = i >> 4, c = i & 15;
    const float4 v =
        *(const float4*)(img + ((size_t)(b * kL + l0 + l)) * kD + d0 + 4 * c);
    float4 o;
    o.x = __builtin_amdgcn_exp2f(kK * v.x);
    o.y = __builtin_amdgcn_exp2f(kK * v.y);
    o.z = __builtin_amdgcn_exp2f(kK * v.z);
    o.w = __builtin_amdgcn_exp2f(kK * v.w);
    Fl4[c * 64 + (l ^ (c & 7))] = o;
  }
  // stage E = 2^(kK*(x+w)) rows 0..31 (30,31 clamp to 29; never stored)
  {
    const int row = tid >> 4, c4 = tid & 15;
    const int tc = (row < kT) ? row : kT - 1;
    const size_t gi = ((size_t)(b * kT + tc)) * kD + d0 + 4 * c4;
    const float4 xv = *(const float4*)(x + gi);
    const float4 wv4 = *(const float4*)(w + gi);
    float4 e;
    e.x = __builtin_amdgcn_exp2f(kK * (xv.x + wv4.x));
    e.y = __builtin_amdgcn_exp2f(kK * (xv.y + wv4.y));
    e.z = __builtin_amdgcn_exp2f(kK * (xv.z + wv4.z));
    e.w = __builtin_amdgcn_exp2f(kK * (xv.w + wv4.w));
    El4[row * 16 + c4] = e;
  }
  if (tid < 16) vwl4[tid] = *(const float4*)(vw + d0 + 4 * tid);
  __syncthreads();
  const int lane = tid & 63, wva = tid >> 6;
  const int tg = wva & 3, dh = wva >> 2;  // t-group, d-half
  const int r0 = tg * 8;
  const float4* Ew = &El4[r0 * 16];
  float acc[8];
#pragma unroll
  for (int tt = 0; tt < 8; ++tt) acc[tt] = 0.f;
#pragma unroll
  for (int s = 0; s < 8; ++s) {
    const int c4 = dh * 8 + s;                  // (c4 & 7) == s
    const float4 f = Fl4[c4 * 64 + (lane ^ s)];  // per-lane, swizzled
    const float4 vv = vwl4[c4];                  // uniform broadcast
#pragma unroll
    for (int tt = 0; tt < 8; ++tt) {
      const float4 E = Ew[tt * 16 + c4];         // uniform broadcast
      PAIR(E.x, E.y, f.x, f.y, vv.x, vv.y, acc[tt]);
      PAIR(E.z, E.w, f.z, f.w, vv.z, vv.w, acc[tt]);
    }
  }
  // merge the two d-halves: dh=1 -> scratch; dh=0 adds and stores
  if (dh == 1) {
#pragma unroll
    for (int tt = 0; tt < 8; ++tt) sc[(tg * 8 + tt) * 64 + lane] = acc[tt];
  }
  __syncthreads();
  if (dh == 0) {
    float* gp =
        g8 + (size_t)dqg * kGsz + ((size_t)(b * kT + r0)) * kL + l0 + lane;
#pragma unroll
    for (int tt = 0; tt < 8; ++tt) {
      if (r0 + tt < kT) {
        gp[(size_t)tt * kL] = acc[tt] + sc[(tg * 8 + tt) * 64 + lane];
      }
    }
  }
}

// softmax over l: l<192 from 8 partials; l=192..195 inline (E from x+w).
// Measured 3.4 us (R11). Unchanged from R13.
__global__ __launch_bounds__(512) void k_alpha(const float* __restrict__ g8,
                                               const float* __restrict__ x,
                                               const float* __restrict__ w,
                                               const float* __restrict__ img,
                                               const float* __restrict__ vw,
                                               float* __restrict__ alpha) {
  const int qd = blockIdx.x, b = blockIdx.y;
  const int lane = threadIdx.x & 63, wv = threadIdx.x >> 6;
  const int t = qd * 8 + wv;
  if (t >= kT) return;
  const int l4 = lane & 3, dc = lane >> 2;
  const float* ir = img + ((size_t)(b * kL + 192 + l4)) * kD + dc * 32;
  const float* xr = x + ((size_t)(b * kT + t)) * kD + dc * 32;
  const float* wr = w + ((size_t)(b * kT + t)) * kD + dc * 32;
  const float* vr = vw + dc * 32;
  float tg = 0.f;
#pragma unroll
  for (int k = 0; k < 8; ++k) {
    const float4 iv = *(const float4*)(ir + 4 * k);
    const float4 xv = *(const float4*)(xr + 4 * k);
    const float4 wv4 = *(const float4*)(wr + 4 * k);
    const float4 vv = *(const float4*)(vr + 4 * k);
    const float fx = __builtin_amdgcn_exp2f(kK * iv.x);
    const float fy = __builtin_amdgcn_exp2f(kK * iv.y);
    const float fz = __builtin_amdgcn_exp2f(kK * iv.z);
    const float fw = __builtin_amdgcn_exp2f(kK * iv.w);
    const float ex = __builtin_amdgcn_exp2f(kK * (xv.x + wv4.x));
    const float ey = __builtin_amdgcn_exp2f(kK * (xv.y + wv4.y));
    const float ez = __builtin_amdgcn_exp2f(kK * (xv.z + wv4.z));
    const float ew = __builtin_amdgcn_exp2f(kK * (xv.w + wv4.w));
    PAIR(ex, ey, fx, fy, vv.x, vv.y, tg);
    PAIR(ez, ew, fz, fw, vv.z, vv.w, tg);
  }
#pragma unroll
  for (int mm = 4; mm < 64; mm <<= 1) tg += __shfl_xor(tg, mm, 64);
  const size_t base = ((size_t)(b * kT + t)) * kL;
  float q0 = 0.f, q1 = 0.f, q2 = 0.f;
#pragma unroll
  for (int p = 0; p < 8; ++p) {
    const float* gp = g8 + (size_t)p * kGsz + base;
    q0 += gp[lane];
    q1 += gp[lane + 64];
    q2 += gp[lane + 128];
  }
  q0 *= kK; q1 *= kK; q2 *= kK;
  float q3 = (lane < 4) ? tg * kK : __builtin_inff();
  float m = fminf(fminf(q0, q1), fminf(q2, q3));
#pragma unroll
  for (int mm = 1; mm < 64; mm <<= 1) m = fminf(m, __shfl_xor(m, mm, 64));
  const float e0 = __builtin_amdgcn_exp2f(m - q0);
  const float e1 = __builtin_amdgcn_exp2f(m - q1);
  const float e2 = __builtin_amdgcn_exp2f(m - q2);
  const float e3 = (lane < 4) ? __builtin_amdgcn_exp2f(m - q3) : 0.f;
  float s = e0 + e1 + e2 + e3;
#pragma unroll
  for (int mm = 1; mm < 64; mm <<= 1) s += __shfl_xor(s, mm, 64);
  const float rs = __builtin_amdgcn_rcpf(s);
  float* ab = alpha + base;
  ab[lane] = e0 * rs;
  ab[lane + 64] = e1 * rs;
  ab[lane + 128] = e2 * rs;
  if (lane < 4) ab[lane + 192] = e3 * rs;
}

// context[b][t][d] = sum_l img[b][l][d]*alpha[b][t][l]. Unchanged from R13.
__global__ __launch_bounds__(256) void k_ctx(const float* __restrict__ img,
                                             const float* __restrict__ alpha,
                                             float* __restrict__ out) {
  __shared__ __align__(16) float red[4][5][256];  // 20 KB
  int n = blockIdx.x;
  const int bg = n & 7;
  int m = n >> 3;  // 48 = 4 bi * 6 tg * 2 dh
  const int bi = m & 3; m >>= 2;
  const int tg = m % 6;
  const int dh = m / 6;
  const int b = bg * 4 + bi;
  const int t0 = tg * 5, d0 = dh * 256;
  const int tid = threadIdx.x;
  const int lane = tid & 63;
  const int lru = __builtin_amdgcn_readfirstlane(tid >> 6);
  const float* ap = alpha + ((size_t)(b * kT + t0)) * kL + lru * 49;  // uniform
  const float* ip = img + ((size_t)(b * kL + lru * 49)) * kD + d0 + 4 * lane;
  float4 acc[5];
#pragma unroll
  for (int j = 0; j < 5; ++j) acc[j] = {0.f, 0.f, 0.f, 0.f};
  auto loadI = [&](float4* dst, int bb) {
#pragma unroll
    for (int j = 0; j < 8; ++j)
      dst[j] = *(const float4*)(ip + (size_t)(bb * 8 + j) * kD);
  };
  auto compI = [&](const float4* f, int bb) {
#pragma unroll
    for (int j = 0; j < 8; ++j) {
      const int i = bb * 8 + j;
      const float a0 = ap[i];
      const float a1 = ap[kL + i];
      const float a2 = ap[2 * kL + i];
      const float a3 = ap[3 * kL + i];
      const float a4 = ap[4 * kL + i];
      acc[0].x = fmaf(f[j].x, a0, acc[0].x); acc[0].y = fmaf(f[j].y, a0, acc[0].y);
      acc[0].z = fmaf(f[j].z, a0, acc[0].z); acc[0].w = fmaf(f[j].w, a0, acc[0].w);
      acc[1].x = fmaf(f[j].x, a1, acc[1].x); acc[1].y = fmaf(f[j].y, a1, acc[1].y);
      acc[1].z = fmaf(f[j].z, a1, acc[1].z); acc[1].w = fmaf(f[j].w, a1, acc[1].w);
      acc[2].x = fmaf(f[j].x, a2, acc[2].x); acc[2].y = fmaf(f[j].y, a2, acc[2].y);
      acc[2].z = fmaf(f[j].z, a2, acc[2].z); acc[2].w = fmaf(f[j].w, a2, acc[2].w);
      acc[3].x = fmaf(f[j].x, a3, acc[3].x); acc[3].y = fmaf(f[j].y, a3, acc[3].y);
      acc[3].z = fmaf(f[j].z, a3, acc[3].z); acc[3].w = fmaf(f[j].w, a3, acc[3].w);
      acc[4].x = fmaf(f[j].x, a4, acc[4].x); acc[4].y = fmaf(f[j].y, a4, acc[4].y);
      acc[4].z = fmaf(f[j].z, a4, acc[4].z); acc[4].w = fmaf(f[j].w, a4, acc[4].w);
    }
  };
  float4 fA[8], fB[8];
  loadI(fA, 0);
  loadI(fB, 1); compI(fA, 0);
  loadI(fA, 2); compI(fB, 1);
  loadI(fB, 3); compI(fA, 2);
  loadI(fA, 4); compI(fB, 3);
  loadI(fB, 5); compI(fA, 4);
  compI(fB, 5);
  {  // tail l-index 48 of this quarter
    const float4 v = *(const float4*)(ip + (size_t)48 * kD);
    const int i = 48;
    const float a0 = ap[i], a1 = ap[kL + i], a2 = ap[2 * kL + i],
                a3 = ap[3 * kL + i], a4 = ap[4 * kL + i];
    acc[0].x = fmaf(v.x, a0, acc[0].x); acc[0].y = fmaf(v.y, a0, acc[0].y);
    acc[0].z = fmaf(v.z, a0, acc[0].z); acc[0].w = fmaf(v.w, a0, acc[0].w);
    acc[1].x = fmaf(v.x, a1, acc[1].x); acc[1].y = fmaf(v.y, a1, acc[1].y);
    acc[1].z = fmaf(v.z, a1, acc[1].z); acc[1].w = fmaf(v.w, a1, acc[1].w);
    acc[2].x = fmaf(v.x, a2, acc[2].x); acc[2].y = fmaf(v.y, a2, acc[2].y);
    acc[2].z = fmaf(v.z, a2, acc[2].z); acc[2].w = fmaf(v.w, a2, acc[2].w);
    acc[3].x = fmaf(v.x, a3, acc[3].x); acc[3].y = fmaf(v.y, a3, acc[3].y);
    acc[3].z = fmaf(v.z, a3, acc[3].z); acc[3].w = fmaf(v.w, a3, acc[3].w);
    acc[4].x = fmaf(v.x, a4, acc[4].x); acc[4].y = fmaf(v.y, a4, acc[4].y);
    acc[4].z = fmaf(v.z, a4, acc[4].z); acc[4].w = fmaf(v.w, a4, acc[4].w);
  }
#pragma unroll
  for (int j = 0; j < 5; ++j) *(float4*)&red[lru][j][4 * lane] = acc[j];
  __syncthreads();
#pragma unroll
  for (int j = 0; j < 5; ++j) {
    const float s =
        red[0][j][tid] + red[1][j][tid] + red[2][j][tid] + red[3][j][tid];
    out[((size_t)(b * kT + t0 + j)) * kD + d0 + tid] = s;
  }
}
}  // namespace

extern "C" void kernel_launch(void* const* d_in, const int* in_sizes, int n_in,
                              void* d_out, int out_size, void* d_ws, size_t ws_size,
                              hipStream_t stream) {
  const float* x = (const float*)d_in[0];
  const float* wordemb = (const float*)d_in[1];
  const float* img = (const float*)d_in[2];
  const float* vw = (const float*)d_in[3];
  // v_b (d_in[4]) cancels in the softmax along with sum(v_w) — unused by design.
  float* out = (float*)d_out;
  float* g8 = (float*)d_ws;        // 6.02 MB
  float* alpha = g8 + 8 * kGsz;    // 0.75 MB
  hipLaunchKernelGGL(k_score, dim3(768), dim3(512), 0, stream, x, wordemb, img,
                     vw, g8);
  hipLaunchKernelGGL(k_alpha, dim3(4, kB), dim3(512), 0, stream, g8, x, wordemb,
                     img, vw, alpha);
  hipLaunchKernelGGL(k_ctx, dim3(384), dim3(256), 0, stream, img, alpha, out);
}

// Round 16
// 28.659 us; speedup vs baseline: 4.1997x; 1.0864x over previous
//
#include <hip/hip_runtime.h>

namespace {
constexpr int kB = 32, kT = 30, kD = 512, kL = 196;
constexpr float kK = 2.8853900817779268f;  // 2*log2(e)
constexpr size_t kGsz = (size_t)kB * kT * kL;  // 188,160

// vwi/u + vwj/v = (vwi*v + vwj*u) * rcp(u*v): 1 rcp per 2 elements
#define PAIR(ex, ey, fx, fy, vx, vy, acc)                                   \
  {                                                                         \
    const float u_ = fmaf(ex, fx, 1.f);                                     \
    const float v_ = fmaf(ey, fy, 1.f);                                     \
    acc = fmaf(fmaf(v_, vx, u_ * vy), __builtin_amdgcn_rcpf(u_ * v_), acc); \
  }

// g8[dqg][b][t][l] (l<192) = sum over 64 d of vw_d/(1+E*F).
// 768 blocks (bg:8 XCD-affine x bi:4 x lc:3 x dqg:8) x 512 thr (8 waves).
// Waves = (tg:4 t-groups x dh:2 d-halves); wave = 8t x 32d x 64l.
// Unchanged from R15 (score ~14us measured-derived).
__global__ __launch_bounds__(512) void k_score(const float* __restrict__ x,
                                               const float* __restrict__ w,
                                               const float* __restrict__ img,
                                               const float* __restrict__ vw,
                                               float* __restrict__ g8) {
  __shared__ __align__(16) float4 Fl4[16 * 64];  // [c][l ^ (c&7)]  16 KB
  __shared__ __align__(16) float4 El4[32 * 16];  // [row][c4]        8 KB
  __shared__ __align__(16) float4 vwl4[16];      //                 256 B
  __shared__ __align__(16) float sc[4 * 8 * 64];  // dh-merge scratch 8 KB
  int n = blockIdx.x;
  const int bg = n & 7;
  int m = n >> 3;  // 96 = 4 bi * 3 lc * 8 dqg
  const int bi = m & 3; m >>= 2;
  const int lc = m % 3;
  const int dqg = m / 3;
  const int b = bg * 4 + bi;
  const int l0 = lc * 64, d0 = dqg * 64;
  const int tid = threadIdx.x;
#pragma unroll
  for (int k = 0; k < 2; ++k) {
    const int i = tid + k * 512;
    const int l = i >> 4, c = i & 15;
    const float4 v =
        *(const float4*)(img + ((size_t)(b * kL + l0 + l)) * kD + d0 + 4 * c);
    float4 o;
    o.x = __builtin_amdgcn_exp2f(kK * v.x);
    o.y = __builtin_amdgcn_exp2f(kK * v.y);
    o.z = __builtin_amdgcn_exp2f(kK * v.z);
    o.w = __builtin_amdgcn_exp2f(kK * v.w);
    Fl4[c * 64 + (l ^ (c & 7))] = o;
  }
  {
    const int row = tid >> 4, c4 = tid & 15;
    const int tc = (row < kT) ? row : kT - 1;
    const size_t gi = ((size_t)(b * kT + tc)) * kD + d0 + 4 * c4;
    const float4 xv = *(const float4*)(x + gi);
    const float4 wv4 = *(const float4*)(w + gi);
    float4 e;
    e.x = __builtin_amdgcn_exp2f(kK * (xv.x + wv4.x));
    e.y = __builtin_amdgcn_exp2f(kK * (xv.y + wv4.y));
    e.z = __builtin_amdgcn_exp2f(kK * (xv.z + wv4.z));
    e.w = __builtin_amdgcn_exp2f(kK * (xv.w + wv4.w));
    El4[row * 16 + c4] = e;
  }
  if (tid < 16) vwl4[tid] = *(const float4*)(vw + d0 + 4 * tid);
  __syncthreads();
  const int lane = tid & 63, wva = tid >> 6;
  const int tg = wva & 3, dh = wva >> 2;  // t-group, d-half
  const int r0 = tg * 8;
  const float4* Ew = &El4[r0 * 16];
  float acc[8];
#pragma unroll
  for (int tt = 0; tt < 8; ++tt) acc[tt] = 0.f;
#pragma unroll
  for (int s = 0; s < 8; ++s) {
    const int c4 = dh * 8 + s;                   // (c4 & 7) == s
    const float4 f = Fl4[c4 * 64 + (lane ^ s)];  // per-lane, swizzled
    const float4 vv = vwl4[c4];                  // uniform broadcast
#pragma unroll
    for (int tt = 0; tt < 8; ++tt) {
      const float4 E = Ew[tt * 16 + c4];  // uniform broadcast
      PAIR(E.x, E.y, f.x, f.y, vv.x, vv.y, acc[tt]);
      PAIR(E.z, E.w, f.z, f.w, vv.z, vv.w, acc[tt]);
    }
  }
  if (dh == 1) {
#pragma unroll
    for (int tt = 0; tt < 8; ++tt) sc[(tg * 8 + tt) * 64 + lane] = acc[tt];
  }
  __syncthreads();
  if (dh == 0) {
    float* gp =
        g8 + (size_t)dqg * kGsz + ((size_t)(b * kT + r0)) * kL + l0 + lane;
#pragma unroll
    for (int tt = 0; tt < 8; ++tt) {
      if (r0 + tt < kT) {
        gp[(size_t)tt * kL] = acc[tt] + sc[(tg * 8 + tt) * 64 + lane];
      }
    }
  }
}

// Fused softmax + context. Grid identical to R13 k_ctx (384, XCD-affine).
// Phase 1: 4 waves compute softmax rows r=wv (+ wv==0: r=4) -> AL2[r][l]
//   (#pragma unroll 1: one softmax body live at a time — R12 spill fix #1).
// Phase 2: R13 ctx with 4-deep dbuf (spill fix #2) + AL2 broadcast reads.
__global__ __launch_bounds__(256) void k_ctxa(const float* __restrict__ g8,
                                              const float* __restrict__ x,
                                              const float* __restrict__ w,
                                              const float* __restrict__ img,
                                              const float* __restrict__ vw,
                                              float* __restrict__ out) {
  __shared__ float AL2[5][200];                   // 4 KB; writes lane-consec
  __shared__ __align__(16) float red[4][5][256];  // 20 KB
  int n = blockIdx.x;
  const int bg = n & 7;
  int m = n >> 3;  // 48 = 4 bi * 6 tg * 2 dh
  const int bi = m & 3; m >>= 2;
  const int tg = m % 6;
  const int dh = m / 6;
  const int b = bg * 4 + bi;
  const int t0 = tg * 5, d0 = dh * 256;
  const int tid = threadIdx.x;
  const int lane = tid & 63;
  const int wv = tid >> 6;
  // ---- phase 1: softmax rows (t = t0 + r <= 29 always) ----
#pragma unroll 1
  for (int r = wv; r < 5; r += 4) {
    const int t = t0 + r;
    const int l4 = lane & 3, dc = lane >> 2;
    const float* ir = img + ((size_t)(b * kL + 192 + l4)) * kD + dc * 32;
    const float* xr = x + ((size_t)(b * kT + t)) * kD + dc * 32;
    const float* wr = w + ((size_t)(b * kT + t)) * kD + dc * 32;
    const float* vr = vw + dc * 32;
    float tgv = 0.f;
#pragma unroll
    for (int k = 0; k < 8; ++k) {
      const float4 iv = *(const float4*)(ir + 4 * k);
      const float4 xv = *(const float4*)(xr + 4 * k);
      const float4 wv4 = *(const float4*)(wr + 4 * k);
      const float4 vv = *(const float4*)(vr + 4 * k);
      const float fx = __builtin_amdgcn_exp2f(kK * iv.x);
      const float fy = __builtin_amdgcn_exp2f(kK * iv.y);
      const float fz = __builtin_amdgcn_exp2f(kK * iv.z);
      const float fw = __builtin_amdgcn_exp2f(kK * iv.w);
      const float ex = __builtin_amdgcn_exp2f(kK * (xv.x + wv4.x));
      const float ey = __builtin_amdgcn_exp2f(kK * (xv.y + wv4.y));
      const float ez = __builtin_amdgcn_exp2f(kK * (xv.z + wv4.z));
      const float ew = __builtin_amdgcn_exp2f(kK * (xv.w + wv4.w));
      PAIR(ex, ey, fx, fy, vv.x, vv.y, tgv);
      PAIR(ez, ew, fz, fw, vv.z, vv.w, tgv);
    }
#pragma unroll
    for (int mm = 4; mm < 64; mm <<= 1) tgv += __shfl_xor(tgv, mm, 64);
    const size_t base = ((size_t)(b * kT + t)) * kL;
    float q0 = 0.f, q1 = 0.f, q2 = 0.f;
#pragma unroll
    for (int p = 0; p < 8; ++p) {
      const float* gp = g8 + (size_t)p * kGsz + base;
      q0 += gp[lane];
      q1 += gp[lane + 64];
      q2 += gp[lane + 128];
    }
    q0 *= kK; q1 *= kK; q2 *= kK;
    float q3 = (lane < 4) ? tgv * kK : __builtin_inff();
    float mn = fminf(fminf(q0, q1), fminf(q2, q3));
#pragma unroll
    for (int mm = 1; mm < 64; mm <<= 1) mn = fminf(mn, __shfl_xor(mn, mm, 64));
    const float e0 = __builtin_amdgcn_exp2f(mn - q0);
    const float e1 = __builtin_amdgcn_exp2f(mn - q1);
    const float e2 = __builtin_amdgcn_exp2f(mn - q2);
    const float e3 = (lane < 4) ? __builtin_amdgcn_exp2f(mn - q3) : 0.f;
    float s = e0 + e1 + e2 + e3;
#pragma unroll
    for (int mm = 1; mm < 64; mm <<= 1) s += __shfl_xor(s, mm, 64);
    const float rs = __builtin_amdgcn_rcpf(s);
    AL2[r][lane] = e0 * rs;
    AL2[r][lane + 64] = e1 * rs;
    AL2[r][lane + 128] = e2 * rs;
    if (lane < 4) AL2[r][lane + 192] = e3 * rs;
  }
  __syncthreads();
  // ---- phase 2: context GEMV (R13 structure, 4-deep dbuf) ----
  const int lru = __builtin_amdgcn_readfirstlane(wv);  // wave's l-quarter
  const float* ip = img + ((size_t)(b * kL + lru * 49)) * kD + d0 + 4 * lane;
  const int lb = lru * 49;
  float4 acc[5];
#pragma unroll
  for (int j = 0; j < 5; ++j) acc[j] = {0.f, 0.f, 0.f, 0.f};
  auto loadI = [&](float4* dst, int bb) {
#pragma unroll
    for (int j = 0; j < 4; ++j)
      dst[j] = *(const float4*)(ip + (size_t)(bb * 4 + j) * kD);
  };
  auto compI = [&](const float4* f, int bb) {
#pragma unroll
    for (int j = 0; j < 4; ++j) {
      const int l = lb + bb * 4 + j;
      const float a0 = AL2[0][l];  // uniform broadcasts (conflict-free)
      const float a1 = AL2[1][l];
      const float a2 = AL2[2][l];
      const float a3 = AL2[3][l];
      const float a4 = AL2[4][l];
      acc[0].x = fmaf(f[j].x, a0, acc[0].x); acc[0].y = fmaf(f[j].y, a0, acc[0].y);
      acc[0].z = fmaf(f[j].z, a0, acc[0].z); acc[0].w = fmaf(f[j].w, a0, acc[0].w);
      acc[1].x = fmaf(f[j].x, a1, acc[1].x); acc[1].y = fmaf(f[j].y, a1, acc[1].y);
      acc[1].z = fmaf(f[j].z, a1, acc[1].z); acc[1].w = fmaf(f[j].w, a1, acc[1].w);
      acc[2].x = fmaf(f[j].x, a2, acc[2].x); acc[2].y = fmaf(f[j].y, a2, acc[2].y);
      acc[2].z = fmaf(f[j].z, a2, acc[2].z); acc[2].w = fmaf(f[j].w, a2, acc[2].w);
      acc[3].x = fmaf(f[j].x, a3, acc[3].x); acc[3].y = fmaf(f[j].y, a3, acc[3].y);
      acc[3].z = fmaf(f[j].z, a3, acc[3].z); acc[3].w = fmaf(f[j].w, a3, acc[3].w);
      acc[4].x = fmaf(f[j].x, a4, acc[4].x); acc[4].y = fmaf(f[j].y, a4, acc[4].y);
      acc[4].z = fmaf(f[j].z, a4, acc[4].z); acc[4].w = fmaf(f[j].w, a4, acc[4].w);
    }
  };
  float4 fA[4], fB[4];
  loadI(fA, 0);
#pragma unroll
  for (int bb = 0; bb < 12; ++bb) {
    if (bb + 1 < 12) {
      if ((bb + 1) & 1) loadI(fB, bb + 1);
      else loadI(fA, bb + 1);
    }
    if (bb & 1) compI(fB, bb);
    else compI(fA, bb);
  }
  {  // tail l-index 48 of this quarter
    const float4 v = *(const float4*)(ip + (size_t)48 * kD);
    const int l = lb + 48;
    const float a0 = AL2[0][l], a1 = AL2[1][l], a2 = AL2[2][l],
                a3 = AL2[3][l], a4 = AL2[4][l];
    acc[0].x = fmaf(v.x, a0, acc[0].x); acc[0].y = fmaf(v.y, a0, acc[0].y);
    acc[0].z = fmaf(v.z, a0, acc[0].z); acc[0].w = fmaf(v.w, a0, acc[0].w);
    acc[1].x = fmaf(v.x, a1, acc[1].x); acc[1].y = fmaf(v.y, a1, acc[1].y);
    acc[1].z = fmaf(v.z, a1, acc[1].z); acc[1].w = fmaf(v.w, a1, acc[1].w);
    acc[2].x = fmaf(v.x, a2, acc[2].x); acc[2].y = fmaf(v.y, a2, acc[2].y);
    acc[2].z = fmaf(v.z, a2, acc[2].z); acc[2].w = fmaf(v.w, a2, acc[2].w);
    acc[3].x = fmaf(v.x, a3, acc[3].x); acc[3].y = fmaf(v.y, a3, acc[3].y);
    acc[3].z = fmaf(v.z, a3, acc[3].z); acc[3].w = fmaf(v.w, a3, acc[3].w);
    acc[4].x = fmaf(v.x, a4, acc[4].x); acc[4].y = fmaf(v.y, a4, acc[4].y);
    acc[4].z = fmaf(v.z, a4, acc[4].z); acc[4].w = fmaf(v.w, a4, acc[4].w);
  }
#pragma unroll
  for (int j = 0; j < 5; ++j) *(float4*)&red[wv][j][4 * lane] = acc[j];
  __syncthreads();
#pragma unroll
  for (int j = 0; j < 5; ++j) {
    const float s =
        red[0][j][tid] + red[1][j][tid] + red[2][j][tid] + red[3][j][tid];
    out[((size_t)(b * kT + t0 + j)) * kD + d0 + tid] = s;
  }
}
}  // namespace

extern "C" void kernel_launch(void* const* d_in, const int* in_sizes, int n_in,
                              void* d_out, int out_size, void* d_ws, size_t ws_size,
                              hipStream_t stream) {
  const float* x = (const float*)d_in[0];
  const float* wordemb = (const float*)d_in[1];
  const float* img = (const float*)d_in[2];
  const float* vw = (const float*)d_in[3];
  // v_b (d_in[4]) cancels in the softmax along with sum(v_w) — unused by design.
  float* out = (float*)d_out;
  float* g8 = (float*)d_ws;  // 6.02 MB
  hipLaunchKernelGGL(k_score, dim3(768), dim3(512), 0, stream, x, wordemb, img,
                     vw, g8);
  hipLaunchKernelGGL(k_ctxa, dim3(384), dim3(256), 0, stream, g8, x, wordemb,
                     img, vw, out);
}